// Round 1
// baseline (483.954 us; speedup 1.0000x reference)
//
#include <hip/hip_runtime.h>

// Problem constants
#define B_ 2
#define L_ 2048
#define D_ 2048
#define NH_ 16
#define KH_ 8
#define HD_ 128

typedef __attribute__((ext_vector_type(8))) short short8;
typedef __attribute__((ext_vector_type(4))) float floatx4;

__device__ __forceinline__ unsigned short f2bf(float f) {
  unsigned u = __float_as_uint(f);
  unsigned r = (u + 0x7fffu + ((u >> 16) & 1u)) >> 16;
  return (unsigned short)r;
}
__device__ __forceinline__ float bf2f(unsigned short h) {
  return __uint_as_float(((unsigned)h) << 16);
}
__device__ __forceinline__ void gl_lds16(const void* g, void* l) {
  __builtin_amdgcn_global_load_lds(
      (const __attribute__((address_space(1))) unsigned int*)g,
      (__attribute__((address_space(3))) unsigned int*)l, 16, 0, 0);
}

// ---------------- convert x: fp32 -> bf16 ----------------
__global__ __launch_bounds__(256) void cvt_f32_bf16(const float* __restrict__ in,
                                                    unsigned short* __restrict__ out) {
  long i = ((long)blockIdx.x * 256 + threadIdx.x) * 4;
  float4 v = *(const float4*)(in + i);
  ushort4 o;
  o.x = f2bf(v.x); o.y = f2bf(v.y); o.z = f2bf(v.z); o.w = f2bf(v.w);
  *(ushort4*)(out + i) = o;
}

// ------------- transpose + convert weights: out[c][r] = in[r][c] -------------
__global__ __launch_bounds__(256) void transpose_cvt(const float* __restrict__ in,
                                                     unsigned short* __restrict__ out,
                                                     int R, int C, int ostride) {
  __shared__ float tile[32][33];
  int c0 = blockIdx.x * 32, r0 = blockIdx.y * 32;
  int tx = threadIdx.x, ty = threadIdx.y;  // (32, 8)
#pragma unroll
  for (int i = 0; i < 4; i++)
    tile[ty + i * 8][tx] = in[(long)(r0 + ty + i * 8) * C + c0 + tx];
  __syncthreads();
#pragma unroll
  for (int i = 0; i < 4; i++) {
    int oc = ty + i * 8;
    out[(long)(c0 + oc) * ostride + r0 + tx] = f2bf(tile[tx][oc]);
  }
}

// ---------------- 128x128-tile bf16 MFMA GEMM:  C = A(MxK) * Bt(NxK)^T ----------------
template <int OUT_BF16>
__global__ __launch_bounds__(256, 2) void gemm128(const unsigned short* __restrict__ A,
                                                  const unsigned short* __restrict__ Bt,
                                                  void* __restrict__ C,
                                                  int M, int N, int K) {
  __shared__ unsigned short As[128 * 64];
  __shared__ unsigned short Bs[128 * 64];
  const int t = threadIdx.x;
  const int lane = t & 63, w = t >> 6;
  const int wy = w >> 1, wx = w & 1;
  const int col = lane & 15, quad = lane >> 4;
  const long m0 = (long)blockIdx.y * 128, n0 = (long)blockIdx.x * 128;
  floatx4 acc[4][4];
#pragma unroll
  for (int i = 0; i < 4; i++)
#pragma unroll
    for (int j = 0; j < 4; j++) acc[i][j] = (floatx4)0.0f;
  const int rs = t >> 3, bs = t & 7;  // staging row / 16B-block
  for (int kt = 0; kt < K; kt += 64) {
#pragma unroll
    for (int i = 0; i < 4; i++) {
      int r = i * 32 + rs;
      gl_lds16(A + (m0 + r) * (long)K + kt + ((bs ^ (r & 7)) << 3),
               &As[(i * 32 + w * 8) * 64]);
      gl_lds16(Bt + (n0 + r) * (long)K + kt + ((bs ^ (r & 7)) << 3),
               &Bs[(i * 32 + w * 8) * 64]);
    }
    __syncthreads();
#pragma unroll
    for (int ks = 0; ks < 2; ks++) {
      short8 af[4], bf[4];
#pragma unroll
      for (int mi = 0; mi < 4; mi++) {
        int row = wy * 64 + mi * 16 + col;
        int blk = ks * 4 + quad;
        af[mi] = *(const short8*)&As[row * 64 + ((blk ^ (row & 7)) << 3)];
      }
#pragma unroll
      for (int ni = 0; ni < 4; ni++) {
        int row = wx * 64 + ni * 16 + col;
        int blk = ks * 4 + quad;
        bf[ni] = *(const short8*)&Bs[row * 64 + ((blk ^ (row & 7)) << 3)];
      }
#pragma unroll
      for (int mi = 0; mi < 4; mi++)
#pragma unroll
        for (int ni = 0; ni < 4; ni++)
          acc[mi][ni] = __builtin_amdgcn_mfma_f32_16x16x32_bf16(af[mi], bf[ni],
                                                                acc[mi][ni], 0, 0, 0);
    }
    __syncthreads();
  }
#pragma unroll
  for (int mi = 0; mi < 4; mi++)
#pragma unroll
    for (int r = 0; r < 4; r++) {
      long row = m0 + wy * 64 + mi * 16 + quad * 4 + r;
#pragma unroll
      for (int ni = 0; ni < 4; ni++) {
        long cg = n0 + wx * 64 + ni * 16 + col;
        float val = acc[mi][ni][r];
        if (OUT_BF16)
          ((unsigned short*)C)[row * N + cg] = f2bf(val);
        else
          ((float*)C)[row * N + cg] = val;
      }
    }
}

// ------------- RMS-norm + RoPE + scale + relayout: one wave per (row, head) -------------
__global__ __launch_bounds__(256) void rmsrope(const unsigned short* __restrict__ qkv,
                                               const int* __restrict__ pos,
                                               const float* __restrict__ qw,
                                               const float* __restrict__ kw,
                                               unsigned short* __restrict__ qo,
                                               unsigned short* __restrict__ ko,
                                               unsigned short* __restrict__ vo) {
  const int t = threadIdx.x, lane = t & 63, w = t >> 6;
  const int gid = blockIdx.x * 4 + w;
  const int hd = gid & 31;   // 0..15 q, 16..23 k, 24..31 v
  const int row = gid >> 5;  // 0..4095 (b*L + l)
  const int b = row >> 11, l = row & 2047;
  const unsigned short* src = qkv + (long)row * 4096 + hd * 128;
  float x0 = bf2f(src[lane]);
  float x1 = bf2f(src[lane + 64]);
  if (hd < 24) {
    float ss = x0 * x0 + x1 * x1;
#pragma unroll
    for (int off = 32; off; off >>= 1) ss += __shfl_xor(ss, off);
    float inv = 1.0f / sqrtf(ss * (1.0f / 128.0f) + 1e-6f);
    const float* nw = (hd < 16) ? qw : kw;
    x0 = nw[lane] * x0 * inv;
    x1 = nw[lane + 64] * x1 * inv;
    float p = (float)pos[row];
    float ts = powf(1.0e6f, (float)lane * (1.0f / 64.0f));
    float ang = p / ts;
    float s, c;
    sincosf(ang, &s, &c);
    float o0 = x0 * c - x1 * s;
    float o1 = x1 * c + x0 * s;
    unsigned short* dst;
    if (hd < 16) {
      o0 *= 0.08838834764831845f;  // fold H^-0.5 into q
      o1 *= 0.08838834764831845f;
      dst = qo + (((long)b * NH_ + hd) * L_ + l) * HD_;
    } else {
      dst = ko + (((long)b * KH_ + (hd - 16)) * L_ + l) * HD_;
    }
    dst[lane] = f2bf(o0);
    dst[lane + 64] = f2bf(o1);
  } else {
    unsigned short* dst = vo + (((long)b * KH_ + (hd - 24)) * L_ + l) * HD_;
    dst[lane] = src[lane];
    dst[lane + 64] = src[lane + 64];
  }
}

// ---------------- flash attention: Q-tile 128, KV-tile 64, GQA group 2 ----------------
__global__ __launch_bounds__(256, 2) void flash(const unsigned short* __restrict__ Q,
                                                const unsigned short* __restrict__ Kg,
                                                const unsigned short* __restrict__ Vg,
                                                unsigned short* __restrict__ Og) {
  __shared__ unsigned short Ks[64 * 128];  // swizzled 16B blocks
  __shared__ unsigned short Vt[128 * 72];  // V^T, row h, stride 72 (16B-aligned reads)
  __shared__ unsigned short Ps[128 * 72];  // P, row l, stride 72
  const int qt = blockIdx.x, n = blockIdx.y, b = blockIdx.z;
  const int t = threadIdx.x, lane = t & 63, w = t >> 6;
  const int col = lane & 15, quad = lane >> 4;
  const int l0 = qt * 128;
  const unsigned short* qb = Q + (((long)b * NH_ + n) * L_ + l0) * HD_;
  const int kvh = n >> 1;
  const unsigned short* kb = Kg + ((long)b * KH_ + kvh) * L_ * HD_;
  const unsigned short* vb = Vg + ((long)b * KH_ + kvh) * L_ * HD_;

  // preload Q fragments (wave w owns rows [32w, 32w+32))
  short8 qf[2][4];
#pragma unroll
  for (int mi = 0; mi < 2; mi++)
#pragma unroll
    for (int ks = 0; ks < 4; ks++)
      qf[mi][ks] = *(const short8*)(qb + (w * 32 + mi * 16 + col) * 128 + ks * 32 + quad * 8);

  floatx4 o[2][8];
#pragma unroll
  for (int mi = 0; mi < 2; mi++)
#pragma unroll
    for (int nf = 0; nf < 8; nf++) o[mi][nf] = (floatx4)0.0f;
  float mrow[2][4], lrow[2][4];
#pragma unroll
  for (int mi = 0; mi < 2; mi++)
#pragma unroll
    for (int r = 0; r < 4; r++) { mrow[mi][r] = -3.0e38f; lrow[mi][r] = 0.0f; }

  const int rK = t >> 4, blkK = t & 15;
  const int nst = 2 * qt + 2;
  for (int st = 0; st < nst; st++) {
    const int s0 = st * 64;
    // stage K tile (64 x 128) via global_load_lds, swizzled low-3 block bits
#pragma unroll
    for (int i = 0; i < 4; i++) {
      int r = i * 16 + rK;
      int gblk = (blkK & 8) | ((blkK ^ r) & 7);
      gl_lds16(kb + (long)(s0 + r) * 128 + gblk * 8, &Ks[(i * 16 + w * 4) * 128]);
    }
    // stage V^T (h-major, stride 72)
#pragma unroll
    for (int j = 0; j < 8; j++) {
      int task = j * 256 + t;
      int h = task & 127, sg = task >> 7;
      ushort4 vv;
      vv.x = vb[(long)(s0 + sg * 4 + 0) * 128 + h];
      vv.y = vb[(long)(s0 + sg * 4 + 1) * 128 + h];
      vv.z = vb[(long)(s0 + sg * 4 + 2) * 128 + h];
      vv.w = vb[(long)(s0 + sg * 4 + 3) * 128 + h];
      *(ushort4*)&Vt[h * 72 + sg * 4] = vv;
    }
    __syncthreads();

    // S = Q K^T  (128 x 64, wave w rows [32w,32w+32))
    floatx4 sa[2][4];
#pragma unroll
    for (int mi = 0; mi < 2; mi++)
#pragma unroll
      for (int sf = 0; sf < 4; sf++) sa[mi][sf] = (floatx4)0.0f;
#pragma unroll
    for (int ks = 0; ks < 4; ks++) {
      short8 bf[4];
#pragma unroll
      for (int sf = 0; sf < 4; sf++) {
        int srow = sf * 16 + col;
        int blk = ks * 4 + quad;
        bf[sf] = *(const short8*)&Ks[srow * 128 + (((blk & 8) | ((blk ^ srow) & 7)) << 3)];
      }
#pragma unroll
      for (int mi = 0; mi < 2; mi++)
#pragma unroll
        for (int sf = 0; sf < 4; sf++)
          sa[mi][sf] = __builtin_amdgcn_mfma_f32_16x16x32_bf16(qf[mi][ks], bf[sf],
                                                               sa[mi][sf], 0, 0, 0);
    }

    // causal mask (only on the two diagonal-touching tiles) + online softmax
    const bool diag = (st >= 2 * qt);
#pragma unroll
    for (int mi = 0; mi < 2; mi++) {
      if (diag) {
#pragma unroll
        for (int sf = 0; sf < 4; sf++)
#pragma unroll
          for (int r = 0; r < 4; r++) {
            int lg = l0 + w * 32 + mi * 16 + quad * 4 + r;
            int sg_ = s0 + sf * 16 + col;
            if (sg_ > lg) sa[mi][sf][r] = -3.0e38f;
          }
      }
#pragma unroll
      for (int r = 0; r < 4; r++) {
        float mx = fmaxf(fmaxf(sa[mi][0][r], sa[mi][1][r]),
                         fmaxf(sa[mi][2][r], sa[mi][3][r]));
#pragma unroll
        for (int off = 8; off; off >>= 1) mx = fmaxf(mx, __shfl_xor(mx, off));
        float mold = mrow[mi][r];
        float mnew = fmaxf(mold, mx);
        float alpha = __expf(mold - mnew);
        float sum = 0.0f;
#pragma unroll
        for (int sf = 0; sf < 4; sf++) {
          float p = __expf(sa[mi][sf][r] - mnew);
          sa[mi][sf][r] = p;
          sum += p;
        }
#pragma unroll
        for (int off = 8; off; off >>= 1) sum += __shfl_xor(sum, off);
        lrow[mi][r] = lrow[mi][r] * alpha + sum;
        mrow[mi][r] = mnew;
#pragma unroll
        for (int nf = 0; nf < 8; nf++) o[mi][nf][r] *= alpha;
      }
    }

    // P -> LDS (A-operand layout)
#pragma unroll
    for (int mi = 0; mi < 2; mi++)
#pragma unroll
      for (int sf = 0; sf < 4; sf++)
#pragma unroll
        for (int r = 0; r < 4; r++) {
          int lr = w * 32 + mi * 16 + quad * 4 + r;
          Ps[lr * 72 + sf * 16 + col] = f2bf(sa[mi][sf][r]);
        }
    __syncthreads();

    // O += P V
#pragma unroll
    for (int ks = 0; ks < 2; ks++) {
      short8 pf[2], vf[8];
#pragma unroll
      for (int mi = 0; mi < 2; mi++)
        pf[mi] = *(const short8*)&Ps[(w * 32 + mi * 16 + col) * 72 + ks * 32 + quad * 8];
#pragma unroll
      for (int nf = 0; nf < 8; nf++)
        vf[nf] = *(const short8*)&Vt[(nf * 16 + col) * 72 + ks * 32 + quad * 8];
#pragma unroll
      for (int mi = 0; mi < 2; mi++)
#pragma unroll
        for (int nf = 0; nf < 8; nf++)
          o[mi][nf] = __builtin_amdgcn_mfma_f32_16x16x32_bf16(pf[mi], vf[nf],
                                                              o[mi][nf], 0, 0, 0);
    }
    __syncthreads();
  }

  // epilogue: O /= l, write (B, L, N, H) bf16
#pragma unroll
  for (int mi = 0; mi < 2; mi++)
#pragma unroll
    for (int r = 0; r < 4; r++) {
      float inv = 1.0f / lrow[mi][r];
      int lg = l0 + w * 32 + mi * 16 + quad * 4 + r;
      unsigned short* dst = Og + (((long)b * L_ + lg) * NH_ + n) * HD_;
#pragma unroll
      for (int nf = 0; nf < 8; nf++)
        dst[nf * 16 + col] = f2bf(o[mi][nf][r] * inv);
    }
}

// ---------------- launcher ----------------
extern "C" void kernel_launch(void* const* d_in, const int* in_sizes, int n_in,
                              void* d_out, int out_size, void* d_ws, size_t ws_size,
                              hipStream_t stream) {
  const float* x = (const float*)d_in[0];
  const int* pos = (const int*)d_in[1];
  // d_in[2] = attn_mask (causal tril) -- implicit in the flash kernel
  const float* wq = (const float*)d_in[3];
  const float* wk = (const float*)d_in[4];
  const float* wv = (const float*)d_in[5];
  const float* wo = (const float*)d_in[6];
  const float* qnw = (const float*)d_in[7];
  const float* knw = (const float*)d_in[8];
  float* out = (float*)d_out;

  // workspace layout (bytes)
  char* ws = (char*)d_ws;
  unsigned short* xb     = (unsigned short*)(ws + 0);          // 16 MiB  (4096 x 2048 bf16)
  unsigned short* wqkv_t = (unsigned short*)(ws + 16777216);   // 16 MiB  (4096 x 2048 bf16)
  unsigned short* wo_t   = (unsigned short*)(ws + 33554432);   //  8 MiB  (2048 x 2048 bf16)
  unsigned short* qkv    = (unsigned short*)(ws + 41943040);   // 32 MiB  (4096 x 4096 bf16)
  unsigned short* q      = (unsigned short*)(ws + 75497472);   // 16 MiB  (B,N,L,H)
  unsigned short* k      = (unsigned short*)(ws + 92274688);   //  8 MiB  (B,K,L,H)
  unsigned short* v      = (unsigned short*)(ws + 100663296);  //  8 MiB  (B,K,L,H)
  unsigned short* ao     = (unsigned short*)(ws + 109051904);  // 16 MiB  (B,L,N,H)
  if (ws_size < 125829120) return;  // insufficient workspace -> fail loudly

  cvt_f32_bf16<<<8192, 256, 0, stream>>>(x, xb);
  dim3 tb(32, 8);
  transpose_cvt<<<dim3(64, 64), tb, 0, stream>>>(wq, wqkv_t, 2048, 2048, 2048);
  transpose_cvt<<<dim3(32, 64), tb, 0, stream>>>(wk, wqkv_t + 2048L * 2048, 2048, 1024, 2048);
  transpose_cvt<<<dim3(32, 64), tb, 0, stream>>>(wv, wqkv_t + 3072L * 2048, 2048, 1024, 2048);
  transpose_cvt<<<dim3(64, 64), tb, 0, stream>>>(wo, wo_t, 2048, 2048, 2048);
  gemm128<1><<<dim3(32, 32), 256, 0, stream>>>(xb, wqkv_t, qkv, 4096, 4096, 2048);
  rmsrope<<<32768, 256, 0, stream>>>(qkv, pos, qnw, knw, q, k, v);
  flash<<<dim3(16, NH_, B_), 256, 0, stream>>>(q, k, v, ao);
  gemm128<0><<<dim3(16, 32), 256, 0, stream>>>(ao, wo_t, out, 4096, 2048, 2048);
}

// Round 2
// 417.301 us; speedup vs baseline: 1.1597x; 1.1597x over previous
//
#include <hip/hip_runtime.h>

// Problem constants
#define B_ 2
#define L_ 2048
#define D_ 2048
#define NH_ 16
#define KH_ 8
#define HD_ 128

typedef __attribute__((ext_vector_type(8))) short short8;
typedef __attribute__((ext_vector_type(4))) float floatx4;

__device__ __forceinline__ unsigned short f2bf(float f) {
  unsigned u = __float_as_uint(f);
  unsigned r = (u + 0x7fffu + ((u >> 16) & 1u)) >> 16;
  return (unsigned short)r;
}
__device__ __forceinline__ float bf2f(unsigned short h) {
  return __uint_as_float(((unsigned)h) << 16);
}
__device__ __forceinline__ void gl_lds16(const void* g, void* l) {
  __builtin_amdgcn_global_load_lds(
      (const __attribute__((address_space(1))) unsigned int*)g,
      (__attribute__((address_space(3))) unsigned int*)l, 16, 0, 0);
}

// ---------------- convert x: fp32 -> bf16 ----------------
__global__ __launch_bounds__(256) void cvt_f32_bf16(const float* __restrict__ in,
                                                    unsigned short* __restrict__ out) {
  long i = ((long)blockIdx.x * 256 + threadIdx.x) * 4;
  float4 v = *(const float4*)(in + i);
  ushort4 o;
  o.x = f2bf(v.x); o.y = f2bf(v.y); o.z = f2bf(v.z); o.w = f2bf(v.w);
  *(ushort4*)(out + i) = o;
}

// ------------- transpose + convert weights: out[c][r] = in[r][c] -------------
__global__ __launch_bounds__(256) void transpose_cvt(const float* __restrict__ in,
                                                     unsigned short* __restrict__ out,
                                                     int R, int C, int ostride) {
  __shared__ float tile[32][33];
  int c0 = blockIdx.x * 32, r0 = blockIdx.y * 32;
  int tx = threadIdx.x, ty = threadIdx.y;  // (32, 8)
#pragma unroll
  for (int i = 0; i < 4; i++)
    tile[ty + i * 8][tx] = in[(long)(r0 + ty + i * 8) * C + c0 + tx];
  __syncthreads();
#pragma unroll
  for (int i = 0; i < 4; i++) {
    int oc = ty + i * 8;
    out[(long)(c0 + oc) * ostride + r0 + tx] = f2bf(tile[tx][oc]);
  }
}

// ------ transpose v slice of qkv (bf16): vT[b][kh][h][l] = qkv[b*L+l][3072+kh*128+h] ------
__global__ __launch_bounds__(256) void transpose_v(const unsigned short* __restrict__ qkv,
                                                   unsigned short* __restrict__ vT) {
  __shared__ unsigned short tile[32][33];
  int l0 = blockIdx.x * 32, h0 = blockIdx.y * 32;
  int bk = blockIdx.z;  // b*8 + kh
  int b = bk >> 3, kh = bk & 7;
  int tx = threadIdx.x, ty = threadIdx.y;  // (32, 8)
  const unsigned short* src = qkv + (long)b * L_ * 4096 + 3072 + kh * 128;
#pragma unroll
  for (int i = 0; i < 4; i++)
    tile[ty + i * 8][tx] = src[(long)(l0 + ty + i * 8) * 4096 + h0 + tx];
  __syncthreads();
  unsigned short* dst = vT + (long)bk * HD_ * L_;
#pragma unroll
  for (int i = 0; i < 4; i++)
    dst[(long)(h0 + ty + i * 8) * L_ + l0 + tx] = tile[tx][ty + i * 8];
}

// ---------------- 128x128-tile bf16 MFMA GEMM:  C = A(MxK) * Bt(NxK)^T ----------------
template <int OUT_BF16>
__global__ __launch_bounds__(256, 2) void gemm128(const unsigned short* __restrict__ A,
                                                  const unsigned short* __restrict__ Bt,
                                                  void* __restrict__ C,
                                                  int M, int N, int K) {
  __shared__ unsigned short As[128 * 64];
  __shared__ unsigned short Bs[128 * 64];
  const int t = threadIdx.x;
  const int lane = t & 63, w = t >> 6;
  const int wy = w >> 1, wx = w & 1;
  const int col = lane & 15, quad = lane >> 4;
  const long m0 = (long)blockIdx.y * 128, n0 = (long)blockIdx.x * 128;
  floatx4 acc[4][4];
#pragma unroll
  for (int i = 0; i < 4; i++)
#pragma unroll
    for (int j = 0; j < 4; j++) acc[i][j] = (floatx4)0.0f;
  const int rs = t >> 3, bs = t & 7;  // staging row / 16B-block
  for (int kt = 0; kt < K; kt += 64) {
#pragma unroll
    for (int i = 0; i < 4; i++) {
      int r = i * 32 + rs;
      gl_lds16(A + (m0 + r) * (long)K + kt + ((bs ^ (r & 7)) << 3),
               &As[(i * 32 + w * 8) * 64]);
      gl_lds16(Bt + (n0 + r) * (long)K + kt + ((bs ^ (r & 7)) << 3),
               &Bs[(i * 32 + w * 8) * 64]);
    }
    __syncthreads();
#pragma unroll
    for (int ks = 0; ks < 2; ks++) {
      short8 af[4], bf[4];
#pragma unroll
      for (int mi = 0; mi < 4; mi++) {
        int row = wy * 64 + mi * 16 + col;
        int blk = ks * 4 + quad;
        af[mi] = *(const short8*)&As[row * 64 + ((blk ^ (row & 7)) << 3)];
      }
#pragma unroll
      for (int ni = 0; ni < 4; ni++) {
        int row = wx * 64 + ni * 16 + col;
        int blk = ks * 4 + quad;
        bf[ni] = *(const short8*)&Bs[row * 64 + ((blk ^ (row & 7)) << 3)];
      }
#pragma unroll
      for (int mi = 0; mi < 4; mi++)
#pragma unroll
        for (int ni = 0; ni < 4; ni++)
          acc[mi][ni] = __builtin_amdgcn_mfma_f32_16x16x32_bf16(af[mi], bf[ni],
                                                                acc[mi][ni], 0, 0, 0);
    }
    __syncthreads();
  }
#pragma unroll
  for (int mi = 0; mi < 4; mi++)
#pragma unroll
    for (int r = 0; r < 4; r++) {
      long row = m0 + wy * 64 + mi * 16 + quad * 4 + r;
#pragma unroll
      for (int ni = 0; ni < 4; ni++) {
        long cg = n0 + wx * 64 + ni * 16 + col;
        float val = acc[mi][ni][r];
        if (OUT_BF16)
          ((unsigned short*)C)[row * N + cg] = f2bf(val);
        else
          ((float*)C)[row * N + cg] = val;
      }
    }
}

// ------------- RMS-norm + RoPE + scale + relayout: one wave per (row, head) -------------
// q scale folds H^-0.5 AND log2(e) (flash softmax uses exp2).
__global__ __launch_bounds__(256) void rmsrope(const unsigned short* __restrict__ qkv,
                                               const int* __restrict__ pos,
                                               const float* __restrict__ qw,
                                               const float* __restrict__ kw,
                                               unsigned short* __restrict__ qo,
                                               unsigned short* __restrict__ ko) {
  const int t = threadIdx.x, lane = t & 63, w = t >> 6;
  const int gid = blockIdx.x * 4 + w;  // 0 .. 4096*24-1
  const int row = gid / 24;
  const int hd = gid - row * 24;  // 0..15 q, 16..23 k
  const int b = row >> 11, l = row & 2047;
  const unsigned short* src = qkv + (long)row * 4096 + hd * 128;
  float x0 = bf2f(src[lane]);
  float x1 = bf2f(src[lane + 64]);
  float ss = x0 * x0 + x1 * x1;
#pragma unroll
  for (int off = 32; off; off >>= 1) ss += __shfl_xor(ss, off);
  float inv = 1.0f / sqrtf(ss * (1.0f / 128.0f) + 1e-6f);
  const float* nw = (hd < 16) ? qw : kw;
  x0 = nw[lane] * x0 * inv;
  x1 = nw[lane + 64] * x1 * inv;
  float p = (float)pos[row];
  float ts = powf(1.0e6f, (float)lane * (1.0f / 64.0f));
  float ang = p / ts;
  float s, c;
  sincosf(ang, &s, &c);
  float o0 = x0 * c - x1 * s;
  float o1 = x1 * c + x0 * s;
  unsigned short* dst;
  if (hd < 16) {
    const float QSC = 0.08838834764831845f * 1.4426950408889634f;  // H^-0.5 * log2e
    o0 *= QSC;
    o1 *= QSC;
    dst = qo + (((long)b * NH_ + hd) * L_ + l) * HD_;
  } else {
    dst = ko + (((long)b * KH_ + (hd - 16)) * L_ + l) * HD_;
  }
  dst[lane] = f2bf(o0);
  dst[lane + 64] = f2bf(o1);
}

// ------- flash attention: paired 64-row Q tiles (perfect balance), KV-tile 64 -------
// block = pair p: Q tiles {p, 31-p} -> every block does exactly 33 KV steps.
__global__ __launch_bounds__(256, 2) void flash(const unsigned short* __restrict__ Q,
                                                const unsigned short* __restrict__ Kg,
                                                const unsigned short* __restrict__ VT,
                                                unsigned short* __restrict__ Og) {
  __shared__ unsigned short Ks[64 * 128];  // K tile, xor-swizzled 16B blocks
  __shared__ unsigned short Vs[128 * 64];  // V^T tile (h-major), xor-swizzled
  __shared__ unsigned short Ps[64 * 72];   // P, row l, stride 72 (144B = 9*16B aligned)
  const int p = blockIdx.x, n = blockIdx.y, b = blockIdx.z;
  const int t = threadIdx.x, lane = t & 63, w = t >> 6;
  const int col = lane & 15, quad = lane >> 4;
  const int kvh = n >> 1;
  const unsigned short* kb = Kg + ((long)b * KH_ + kvh) * L_ * HD_;
  const unsigned short* vtb = VT + ((long)b * KH_ + kvh) * HD_ * L_;  // [h][l]

  for (int phase = 0; phase < 2; phase++) {
    const int qtile = phase ? (31 - p) : p;
    const int l0 = qtile * 64;
    const int steps = qtile + 1;
    const unsigned short* qb = Q + (((long)b * NH_ + n) * L_ + l0) * HD_;

    // wave w owns Q rows [16w, 16w+16)
    short8 qf[4];
#pragma unroll
    for (int ks = 0; ks < 4; ks++)
      qf[ks] = *(const short8*)(qb + (w * 16 + col) * 128 + ks * 32 + quad * 8);

    floatx4 o[8];
#pragma unroll
    for (int nf = 0; nf < 8; nf++) o[nf] = (floatx4)0.0f;
    float mrow[4], lrow[4];
#pragma unroll
    for (int r = 0; r < 4; r++) { mrow[r] = -3.0e38f; lrow[r] = 0.0f; }

    for (int st = 0; st < steps; st++) {
      const int s0 = st * 64;
      // stage K tile (64 x 128): 4 x gl_lds16 per thread
      {
        const int rK = t >> 4, blkK = t & 15;
#pragma unroll
        for (int i = 0; i < 4; i++) {
          int r = i * 16 + rK;
          int gblk = (blkK & 8) | ((blkK ^ r) & 7);
          gl_lds16(kb + (long)(s0 + r) * 128 + gblk * 8, &Ks[(i * 16 + w * 4) * 128]);
        }
      }
      // stage V^T tile (128 x 64): 4 x gl_lds16 per thread
      {
        const int rV = t >> 3, blkV = t & 7;
#pragma unroll
        for (int j = 0; j < 4; j++) {
          int r = j * 32 + rV;
          int gblk = (blkV ^ r) & 7;
          gl_lds16(vtb + (long)r * L_ + s0 + gblk * 8, &Vs[(j * 32 + w * 8) * 64]);
        }
      }
      __syncthreads();

      // S = Q K^T  (16 rows per wave x 64 cols)
      floatx4 sa[4];
#pragma unroll
      for (int sf = 0; sf < 4; sf++) sa[sf] = (floatx4)0.0f;
#pragma unroll
      for (int ks = 0; ks < 4; ks++) {
        short8 bf[4];
#pragma unroll
        for (int sf = 0; sf < 4; sf++) {
          int srow = sf * 16 + col;
          int blk = ks * 4 + quad;
          bf[sf] = *(const short8*)&Ks[srow * 128 + (((blk & 8) | ((blk ^ srow) & 7)) << 3)];
        }
#pragma unroll
        for (int sf = 0; sf < 4; sf++)
          sa[sf] = __builtin_amdgcn_mfma_f32_16x16x32_bf16(qf[ks], bf[sf], sa[sf], 0, 0, 0);
      }

      // causal mask only on the diagonal step
      if (st == steps - 1) {
#pragma unroll
        for (int sf = 0; sf < 4; sf++)
#pragma unroll
          for (int r = 0; r < 4; r++) {
            int lr = w * 16 + quad * 4 + r;
            int sr = sf * 16 + col;
            if (sr > lr) sa[sf][r] = -3.0e38f;
          }
      }

      // online softmax (exp2 domain; log2e folded into q)
#pragma unroll
      for (int r = 0; r < 4; r++) {
        float mx = fmaxf(fmaxf(sa[0][r], sa[1][r]), fmaxf(sa[2][r], sa[3][r]));
#pragma unroll
        for (int off = 8; off; off >>= 1) mx = fmaxf(mx, __shfl_xor(mx, off));
        float mold = mrow[r];
        float mnew = fmaxf(mold, mx);
        float alpha = exp2f(mold - mnew);
        float sum = 0.0f;
#pragma unroll
        for (int sf = 0; sf < 4; sf++) {
          float pv = exp2f(sa[sf][r] - mnew);
          sa[sf][r] = pv;
          sum += pv;
        }
#pragma unroll
        for (int off = 8; off; off >>= 1) sum += __shfl_xor(sum, off);
        lrow[r] = lrow[r] * alpha + sum;
        mrow[r] = mnew;
#pragma unroll
        for (int nf = 0; nf < 8; nf++) o[nf][r] *= alpha;
      }

      // P -> LDS (A-operand layout); own rows only, no barrier needed
#pragma unroll
      for (int sf = 0; sf < 4; sf++)
#pragma unroll
        for (int r = 0; r < 4; r++)
          Ps[(w * 16 + quad * 4 + r) * 72 + sf * 16 + col] = f2bf(sa[sf][r]);

      // O += P V
#pragma unroll
      for (int ks = 0; ks < 2; ks++) {
        short8 pf = *(const short8*)&Ps[(w * 16 + col) * 72 + ks * 32 + quad * 8];
        short8 vf[8];
#pragma unroll
        for (int nf = 0; nf < 8; nf++) {
          int h = nf * 16 + col;
          int blk = ks * 4 + quad;
          vf[nf] = *(const short8*)&Vs[h * 64 + ((blk ^ (h & 7)) << 3)];
        }
#pragma unroll
        for (int nf = 0; nf < 8; nf++)
          o[nf] = __builtin_amdgcn_mfma_f32_16x16x32_bf16(pf, vf[nf], o[nf], 0, 0, 0);
      }
      __syncthreads();
    }

    // epilogue: O /= l, write (B, L, N, H) bf16
#pragma unroll
    for (int r = 0; r < 4; r++) {
      float inv = 1.0f / lrow[r];
      int lg = l0 + w * 16 + quad * 4 + r;
      unsigned short* dst = Og + (((long)b * L_ + lg) * NH_ + n) * HD_;
#pragma unroll
      for (int nf = 0; nf < 8; nf++)
        dst[nf * 16 + col] = f2bf(o[nf][r] * inv);
    }
  }
}

// ---------------- launcher ----------------
extern "C" void kernel_launch(void* const* d_in, const int* in_sizes, int n_in,
                              void* d_out, int out_size, void* d_ws, size_t ws_size,
                              hipStream_t stream) {
  const float* x = (const float*)d_in[0];
  const int* pos = (const int*)d_in[1];
  // d_in[2] = attn_mask (causal tril) -- implicit in the flash kernel
  const float* wq = (const float*)d_in[3];
  const float* wk = (const float*)d_in[4];
  const float* wv = (const float*)d_in[5];
  const float* wo = (const float*)d_in[6];
  const float* qnw = (const float*)d_in[7];
  const float* knw = (const float*)d_in[8];
  float* out = (float*)d_out;

  // workspace layout (bytes)
  char* ws = (char*)d_ws;
  unsigned short* xb     = (unsigned short*)(ws + 0);          // 16 MiB  (4096 x 2048 bf16)
  unsigned short* wqkv_t = (unsigned short*)(ws + 16777216);   // 16 MiB  (4096 x 2048 bf16)
  unsigned short* wo_t   = (unsigned short*)(ws + 33554432);   //  8 MiB  (2048 x 2048 bf16)
  unsigned short* qkv    = (unsigned short*)(ws + 41943040);   // 32 MiB  (4096 x 4096 bf16)
  unsigned short* q      = (unsigned short*)(ws + 75497472);   // 16 MiB  (B,N,L,H)
  unsigned short* k      = (unsigned short*)(ws + 92274688);   //  8 MiB  (B,K,L,H)
  unsigned short* vT     = (unsigned short*)(ws + 100663296);  //  8 MiB  (B,K,H,L)
  unsigned short* ao     = (unsigned short*)(ws + 109051904);  // 16 MiB  (B,L,N,H)
  if (ws_size < 125829120) return;  // insufficient workspace -> fail loudly

  cvt_f32_bf16<<<8192, 256, 0, stream>>>(x, xb);
  dim3 tb(32, 8);
  transpose_cvt<<<dim3(64, 64), tb, 0, stream>>>(wq, wqkv_t, 2048, 2048, 2048);
  transpose_cvt<<<dim3(32, 64), tb, 0, stream>>>(wk, wqkv_t + 2048L * 2048, 2048, 1024, 2048);
  transpose_cvt<<<dim3(32, 64), tb, 0, stream>>>(wv, wqkv_t + 3072L * 2048, 2048, 1024, 2048);
  transpose_cvt<<<dim3(64, 64), tb, 0, stream>>>(wo, wo_t, 2048, 2048, 2048);
  gemm128<1><<<dim3(32, 32), 256, 0, stream>>>(xb, wqkv_t, qkv, 4096, 4096, 2048);
  rmsrope<<<24576, 256, 0, stream>>>(qkv, pos, qnw, knw, q, k);
  transpose_v<<<dim3(64, 4, 16), tb, 0, stream>>>(qkv, vT);
  flash<<<dim3(16, NH_, B_), 256, 0, stream>>>(q, k, vT, ao);
  gemm128<0><<<dim3(16, 32), 256, 0, stream>>>(ao, wo_t, out, 4096, 2048, 2048);
}

// Round 3
// 393.482 us; speedup vs baseline: 1.2299x; 1.0605x over previous
//
#include <hip/hip_runtime.h>

// Problem constants
#define B_ 2
#define L_ 2048
#define D_ 2048
#define NH_ 16
#define KH_ 8
#define HD_ 128

typedef __attribute__((ext_vector_type(8))) short short8;
typedef __attribute__((ext_vector_type(4))) float floatx4;

__device__ __forceinline__ unsigned short f2bf(float f) {
  unsigned u = __float_as_uint(f);
  unsigned r = (u + 0x7fffu + ((u >> 16) & 1u)) >> 16;
  return (unsigned short)r;
}
__device__ __forceinline__ float bf2f(unsigned short h) {
  return __uint_as_float(((unsigned)h) << 16);
}
__device__ __forceinline__ void gl_lds16(const void* g, void* l) {
  __builtin_amdgcn_global_load_lds(
      (const __attribute__((address_space(1))) unsigned int*)g,
      (__attribute__((address_space(3))) unsigned int*)l, 16, 0, 0);
}

// ---------------- convert x: fp32 -> bf16 ----------------
__global__ __launch_bounds__(256) void cvt_f32_bf16(const float* __restrict__ in,
                                                    unsigned short* __restrict__ out) {
  long i = ((long)blockIdx.x * 256 + threadIdx.x) * 4;
  float4 v = *(const float4*)(in + i);
  ushort4 o;
  o.x = f2bf(v.x); o.y = f2bf(v.y); o.z = f2bf(v.z); o.w = f2bf(v.w);
  *(ushort4*)(out + i) = o;
}

// ------------- transpose + convert weights: out[c][r] = in[r][c] -------------
__global__ __launch_bounds__(256) void transpose_cvt(const float* __restrict__ in,
                                                     unsigned short* __restrict__ out,
                                                     int R, int C, int ostride) {
  __shared__ float tile[32][33];
  int c0 = blockIdx.x * 32, r0 = blockIdx.y * 32;
  int tx = threadIdx.x, ty = threadIdx.y;  // (32, 8)
#pragma unroll
  for (int i = 0; i < 4; i++)
    tile[ty + i * 8][tx] = in[(long)(r0 + ty + i * 8) * C + c0 + tx];
  __syncthreads();
#pragma unroll
  for (int i = 0; i < 4; i++) {
    int oc = ty + i * 8;
    out[(long)(c0 + oc) * ostride + r0 + tx] = f2bf(tile[tx][oc]);
  }
}

// ------ transpose v slice of qkv (bf16): vT[b][kh][h][l] = qkv[b*L+l][3072+kh*128+h] ------
__global__ __launch_bounds__(256) void transpose_v(const unsigned short* __restrict__ qkv,
                                                   unsigned short* __restrict__ vT) {
  __shared__ unsigned short tile[32][33];
  int l0 = blockIdx.x * 32, h0 = blockIdx.y * 32;
  int bk = blockIdx.z;  // b*8 + kh
  int b = bk >> 3, kh = bk & 7;
  int tx = threadIdx.x, ty = threadIdx.y;  // (32, 8)
  const unsigned short* src = qkv + (long)b * L_ * 4096 + 3072 + kh * 128;
#pragma unroll
  for (int i = 0; i < 4; i++)
    tile[ty + i * 8][tx] = src[(long)(l0 + ty + i * 8) * 4096 + h0 + tx];
  __syncthreads();
  unsigned short* dst = vT + (long)bk * HD_ * L_;
#pragma unroll
  for (int i = 0; i < 4; i++)
    dst[(long)(h0 + ty + i * 8) * L_ + l0 + tx] = tile[tx][ty + i * 8];
}

// ---------------- 128x128-tile bf16 MFMA GEMM:  C = A(MxK) * Bt(NxK)^T ----------------
template <int OUT_BF16>
__global__ __launch_bounds__(256, 2) void gemm128(const unsigned short* __restrict__ A,
                                                  const unsigned short* __restrict__ Bt,
                                                  void* __restrict__ C,
                                                  int M, int N, int K) {
  __shared__ unsigned short As[128 * 64];
  __shared__ unsigned short Bs[128 * 64];
  const int t = threadIdx.x;
  const int lane = t & 63, w = t >> 6;
  const int wy = w >> 1, wx = w & 1;
  const int col = lane & 15, quad = lane >> 4;
  const long m0 = (long)blockIdx.y * 128, n0 = (long)blockIdx.x * 128;
  floatx4 acc[4][4];
#pragma unroll
  for (int i = 0; i < 4; i++)
#pragma unroll
    for (int j = 0; j < 4; j++) acc[i][j] = (floatx4)0.0f;
  const int rs = t >> 3, bs = t & 7;  // staging row / 16B-block
  for (int kt = 0; kt < K; kt += 64) {
#pragma unroll
    for (int i = 0; i < 4; i++) {
      int r = i * 32 + rs;
      gl_lds16(A + (m0 + r) * (long)K + kt + ((bs ^ (r & 7)) << 3),
               &As[(i * 32 + w * 8) * 64]);
      gl_lds16(Bt + (n0 + r) * (long)K + kt + ((bs ^ (r & 7)) << 3),
               &Bs[(i * 32 + w * 8) * 64]);
    }
    __syncthreads();
#pragma unroll
    for (int ks = 0; ks < 2; ks++) {
      short8 af[4], bf[4];
#pragma unroll
      for (int mi = 0; mi < 4; mi++) {
        int row = wy * 64 + mi * 16 + col;
        int blk = ks * 4 + quad;
        af[mi] = *(const short8*)&As[row * 64 + ((blk ^ (row & 7)) << 3)];
      }
#pragma unroll
      for (int ni = 0; ni < 4; ni++) {
        int row = wx * 64 + ni * 16 + col;
        int blk = ks * 4 + quad;
        bf[ni] = *(const short8*)&Bs[row * 64 + ((blk ^ (row & 7)) << 3)];
      }
#pragma unroll
      for (int mi = 0; mi < 4; mi++)
#pragma unroll
        for (int ni = 0; ni < 4; ni++)
          acc[mi][ni] = __builtin_amdgcn_mfma_f32_16x16x32_bf16(af[mi], bf[ni],
                                                                acc[mi][ni], 0, 0, 0);
    }
    __syncthreads();
  }
#pragma unroll
  for (int mi = 0; mi < 4; mi++)
#pragma unroll
    for (int r = 0; r < 4; r++) {
      long row = m0 + wy * 64 + mi * 16 + quad * 4 + r;
#pragma unroll
      for (int ni = 0; ni < 4; ni++) {
        long cg = n0 + wx * 64 + ni * 16 + col;
        float val = acc[mi][ni][r];
        if (OUT_BF16)
          ((unsigned short*)C)[row * N + cg] = f2bf(val);
        else
          ((float*)C)[row * N + cg] = val;
      }
    }
}

// ------------- RMS-norm + RoPE + scale + relayout: one wave per (row, head) -------------
// q scale folds H^-0.5 AND log2(e) (flash softmax uses exp2).
__global__ __launch_bounds__(256) void rmsrope(const unsigned short* __restrict__ qkv,
                                               const int* __restrict__ pos,
                                               const float* __restrict__ qw,
                                               const float* __restrict__ kw,
                                               unsigned short* __restrict__ qo,
                                               unsigned short* __restrict__ ko) {
  const int t = threadIdx.x, lane = t & 63, w = t >> 6;
  const int gid = blockIdx.x * 4 + w;  // 0 .. 4096*24-1
  const int row = gid / 24;
  const int hd = gid - row * 24;  // 0..15 q, 16..23 k
  const int b = row >> 11, l = row & 2047;
  const unsigned short* src = qkv + (long)row * 4096 + hd * 128;
  float x0 = bf2f(src[lane]);
  float x1 = bf2f(src[lane + 64]);
  float ss = x0 * x0 + x1 * x1;
#pragma unroll
  for (int off = 32; off; off >>= 1) ss += __shfl_xor(ss, off);
  float inv = 1.0f / sqrtf(ss * (1.0f / 128.0f) + 1e-6f);
  const float* nw = (hd < 16) ? qw : kw;
  x0 = nw[lane] * x0 * inv;
  x1 = nw[lane + 64] * x1 * inv;
  float p = (float)pos[row];
  float ts = powf(1.0e6f, (float)lane * (1.0f / 64.0f));
  float ang = p / ts;
  float s, c;
  sincosf(ang, &s, &c);
  float o0 = x0 * c - x1 * s;
  float o1 = x1 * c + x0 * s;
  unsigned short* dst;
  if (hd < 16) {
    const float QSC = 0.08838834764831845f * 1.4426950408889634f;  // H^-0.5 * log2e
    o0 *= QSC;
    o1 *= QSC;
    dst = qo + (((long)b * NH_ + hd) * L_ + l) * HD_;
  } else {
    dst = ko + (((long)b * KH_ + (hd - 16)) * L_ + l) * HD_;
  }
  dst[lane] = f2bf(o0);
  dst[lane + 64] = f2bf(o1);
}

// ------- flash attention: Q-tile 128 (4 waves x 32 rows), KV-tile 64 -------
// Fixed-max softmax: after rms-norm ||q||=||k||=sqrt(H) exactly (RoPE is a
// rotation), so |q.k| * H^-0.5 * log2e <= 16.33 < 17. p = exp2(s - 17) needs
// no running max, no rescale, no per-step cross-lane reductions.
// Grid balance: qt = bx (b=0) / 15-bx (b=1) -> co-resident pairs sum to 34 steps.
__global__ __launch_bounds__(256, 2) void flash(const unsigned short* __restrict__ Q,
                                                const unsigned short* __restrict__ Kg,
                                                const unsigned short* __restrict__ VT,
                                                unsigned short* __restrict__ Og) {
  __shared__ unsigned short Ks[64 * 128];  // K tile, xor-swizzled 16B blocks
  __shared__ unsigned short Vs[128 * 64];  // V^T tile (h-major), xor-swizzled
  __shared__ unsigned short Ps[128 * 72];  // P, row l, stride 72
  const int n = blockIdx.y, b = blockIdx.z;
  const int qt = b ? (15 - blockIdx.x) : blockIdx.x;
  const int t = threadIdx.x, lane = t & 63, w = t >> 6;
  const int col = lane & 15, quad = lane >> 4;
  const int kvh = n >> 1;
  const unsigned short* kb = Kg + ((long)b * KH_ + kvh) * L_ * HD_;
  const unsigned short* vtb = VT + ((long)b * KH_ + kvh) * HD_ * L_;  // [h][l]
  const int l0 = qt * 128;
  const int steps = 2 * qt + 2;
  const unsigned short* qb = Q + (((long)b * NH_ + n) * L_ + l0) * HD_;

  // wave w owns Q rows [32w, 32w+32): 2 m-frags
  short8 qf[2][4];
#pragma unroll
  for (int mi = 0; mi < 2; mi++)
#pragma unroll
    for (int ks = 0; ks < 4; ks++)
      qf[mi][ks] = *(const short8*)(qb + (w * 32 + mi * 16 + col) * 128 + ks * 32 + quad * 8);

  floatx4 o[2][8];
#pragma unroll
  for (int mi = 0; mi < 2; mi++)
#pragma unroll
    for (int nf = 0; nf < 8; nf++) o[mi][nf] = (floatx4)0.0f;
  float lrow[2][4];
#pragma unroll
  for (int mi = 0; mi < 2; mi++)
#pragma unroll
    for (int r = 0; r < 4; r++) lrow[mi][r] = 0.0f;

  for (int st = 0; st < steps; st++) {
    const int s0 = st * 64;
    // stage K tile (64 x 128): 4 x gl_lds16 per thread
    {
      const int rK = t >> 4, blkK = t & 15;
#pragma unroll
      for (int i = 0; i < 4; i++) {
        int r = i * 16 + rK;
        int gblk = (blkK & 8) | ((blkK ^ r) & 7);
        gl_lds16(kb + (long)(s0 + r) * 128 + gblk * 8, &Ks[(i * 16 + w * 4) * 128]);
      }
    }
    // stage V^T tile (128 x 64): 4 x gl_lds16 per thread
    {
      const int rV = t >> 3, blkV = t & 7;
#pragma unroll
      for (int j = 0; j < 4; j++) {
        int r = j * 32 + rV;
        int gblk = (blkV ^ r) & 7;
        gl_lds16(vtb + (long)r * L_ + s0 + gblk * 8, &Vs[(j * 32 + w * 8) * 64]);
      }
    }
    __syncthreads();

    // S = Q K^T  (32 rows per wave x 64 cols)
    floatx4 sa[2][4];
#pragma unroll
    for (int mi = 0; mi < 2; mi++)
#pragma unroll
      for (int sf = 0; sf < 4; sf++) sa[mi][sf] = (floatx4)0.0f;
#pragma unroll
    for (int ks = 0; ks < 4; ks++) {
      short8 bf[4];
#pragma unroll
      for (int sf = 0; sf < 4; sf++) {
        int srow = sf * 16 + col;
        int blk = ks * 4 + quad;
        bf[sf] = *(const short8*)&Ks[srow * 128 + (((blk & 8) | ((blk ^ srow) & 7)) << 3)];
      }
#pragma unroll
      for (int mi = 0; mi < 2; mi++)
#pragma unroll
        for (int sf = 0; sf < 4; sf++)
          sa[mi][sf] = __builtin_amdgcn_mfma_f32_16x16x32_bf16(qf[mi][ks], bf[sf],
                                                               sa[mi][sf], 0, 0, 0);
    }

    // causal mask: only the last two steps touch the diagonal
    if (st >= steps - 2) {
#pragma unroll
      for (int mi = 0; mi < 2; mi++)
#pragma unroll
        for (int sf = 0; sf < 4; sf++)
#pragma unroll
          for (int r = 0; r < 4; r++) {
            int lr = l0 + w * 32 + mi * 16 + quad * 4 + r;
            int sr = s0 + sf * 16 + col;
            if (sr > lr) sa[mi][sf][r] = -3.0e38f;
          }
    }

    // fixed-max softmax: p = exp2(s - 17); per-lane partial row sums only
#pragma unroll
    for (int mi = 0; mi < 2; mi++)
#pragma unroll
      for (int sf = 0; sf < 4; sf++)
#pragma unroll
        for (int r = 0; r < 4; r++) {
          float pv = exp2f(sa[mi][sf][r] - 17.0f);
          sa[mi][sf][r] = pv;
          lrow[mi][r] += pv;
        }

    // P -> LDS (A-operand layout); own rows only, no barrier needed
#pragma unroll
    for (int mi = 0; mi < 2; mi++)
#pragma unroll
      for (int sf = 0; sf < 4; sf++)
#pragma unroll
        for (int r = 0; r < 4; r++)
          Ps[(w * 32 + mi * 16 + quad * 4 + r) * 72 + sf * 16 + col] = f2bf(sa[mi][sf][r]);

    // O += P V
#pragma unroll
    for (int ks = 0; ks < 2; ks++) {
      short8 pf[2];
#pragma unroll
      for (int mi = 0; mi < 2; mi++)
        pf[mi] = *(const short8*)&Ps[(w * 32 + mi * 16 + col) * 72 + ks * 32 + quad * 8];
      short8 vf[8];
#pragma unroll
      for (int nf = 0; nf < 8; nf++) {
        int h = nf * 16 + col;
        int blk = ks * 4 + quad;
        vf[nf] = *(const short8*)&Vs[h * 64 + ((blk ^ (h & 7)) << 3)];
      }
#pragma unroll
      for (int mi = 0; mi < 2; mi++)
#pragma unroll
        for (int nf = 0; nf < 8; nf++)
          o[mi][nf] = __builtin_amdgcn_mfma_f32_16x16x32_bf16(pf[mi], vf[nf],
                                                              o[mi][nf], 0, 0, 0);
    }
    __syncthreads();
  }

  // epilogue: reduce lrow across the 16 col-lanes, O /= l, write (B, L, N, H)
#pragma unroll
  for (int mi = 0; mi < 2; mi++)
#pragma unroll
    for (int r = 0; r < 4; r++) {
      float s = lrow[mi][r];
#pragma unroll
      for (int off = 8; off; off >>= 1) s += __shfl_xor(s, off);
      float inv = 1.0f / s;
      int lg = l0 + w * 32 + mi * 16 + quad * 4 + r;
      unsigned short* dst = Og + (((long)b * L_ + lg) * NH_ + n) * HD_;
#pragma unroll
      for (int nf = 0; nf < 8; nf++)
        dst[nf * 16 + col] = f2bf(o[mi][nf][r] * inv);
    }
}

// ---------------- launcher ----------------
extern "C" void kernel_launch(void* const* d_in, const int* in_sizes, int n_in,
                              void* d_out, int out_size, void* d_ws, size_t ws_size,
                              hipStream_t stream) {
  const float* x = (const float*)d_in[0];
  const int* pos = (const int*)d_in[1];
  // d_in[2] = attn_mask (causal tril) -- implicit in the flash kernel
  const float* wq = (const float*)d_in[3];
  const float* wk = (const float*)d_in[4];
  const float* wv = (const float*)d_in[5];
  const float* wo = (const float*)d_in[6];
  const float* qnw = (const float*)d_in[7];
  const float* knw = (const float*)d_in[8];
  float* out = (float*)d_out;

  // workspace layout (bytes)
  char* ws = (char*)d_ws;
  unsigned short* xb     = (unsigned short*)(ws + 0);          // 16 MiB  (4096 x 2048 bf16)
  unsigned short* wqkv_t = (unsigned short*)(ws + 16777216);   // 16 MiB  (4096 x 2048 bf16)
  unsigned short* wo_t   = (unsigned short*)(ws + 33554432);   //  8 MiB  (2048 x 2048 bf16)
  unsigned short* qkv    = (unsigned short*)(ws + 41943040);   // 32 MiB  (4096 x 4096 bf16)
  unsigned short* q      = (unsigned short*)(ws + 75497472);   // 16 MiB  (B,N,L,H)
  unsigned short* k      = (unsigned short*)(ws + 92274688);   //  8 MiB  (B,K,L,H)
  unsigned short* vT     = (unsigned short*)(ws + 100663296);  //  8 MiB  (B,K,H,L)
  unsigned short* ao     = (unsigned short*)(ws + 109051904);  // 16 MiB  (B,L,N,H)
  if (ws_size < 125829120) return;  // insufficient workspace -> fail loudly

  cvt_f32_bf16<<<8192, 256, 0, stream>>>(x, xb);
  dim3 tb(32, 8);
  transpose_cvt<<<dim3(64, 64), tb, 0, stream>>>(wq, wqkv_t, 2048, 2048, 2048);
  transpose_cvt<<<dim3(32, 64), tb, 0, stream>>>(wk, wqkv_t + 2048L * 2048, 2048, 1024, 2048);
  transpose_cvt<<<dim3(32, 64), tb, 0, stream>>>(wv, wqkv_t + 3072L * 2048, 2048, 1024, 2048);
  transpose_cvt<<<dim3(64, 64), tb, 0, stream>>>(wo, wo_t, 2048, 2048, 2048);
  gemm128<1><<<dim3(32, 32), 256, 0, stream>>>(xb, wqkv_t, qkv, 4096, 4096, 2048);
  rmsrope<<<24576, 256, 0, stream>>>(qkv, pos, qnw, knw, q, k);
  transpose_v<<<dim3(64, 4, 16), tb, 0, stream>>>(qkv, vT);
  flash<<<dim3(16, NH_, B_), 256, 0, stream>>>(q, k, vT, ao);
  gemm128<0><<<dim3(16, 32), 256, 0, stream>>>(ao, wo_t, out, 4096, 2048, 2048);
}